// Round 17
// baseline (152.426 us; speedup 1.0000x reference)
//
#include <hip/hip_runtime.h>
#include <hip/hip_bf16.h>

#define N_NODES 100000
#define N_EDGES 1600000
#define IN_DIM 128
#define HID 64
#define OUT_DIM 32
#define LN_EPS 1e-5f
#define NBKT 782            // ceil(100000/128) coarse buckets (128 nodes each)
#define NPBLK 500           // partition blocks
#define PAIRS_PER_BLK 1600  // 500*1600*2 = 1.6M edges
#define G0T 1563            // gemm0 row-tiles: ceil(100000/64)
#define PADCAP 896          // max padding per bucket (128 nodes * 7, pad-to-8)

typedef __attribute__((ext_vector_type(8))) _Float16 half8;
typedef __attribute__((ext_vector_type(8))) short short8;
typedef __attribute__((ext_vector_type(4))) float f32x4;
typedef __attribute__((ext_vector_type(2))) float f32x2;

__device__ __forceinline__ float uflo(unsigned int u) {
  return __uint_as_float(u << 16);
}
__device__ __forceinline__ float ufhi(unsigned int u) {
  return __uint_as_float(u & 0xffff0000u);
}
__device__ __forceinline__ unsigned short bf16rne(float f) {
  unsigned int u = __float_as_uint(f);
  unsigned int r = u + 0x7fffu + ((u >> 16) & 1u);
  return (unsigned short)(r >> 16);
}
__device__ __forceinline__ unsigned int pk(float lo, float hi) {
  return (unsigned int)bf16rne(lo) | ((unsigned int)bf16rne(hi) << 16);
}
// fp8 e4m3 (OCP) helpers — HW converts on gfx950.
// Word-select of cvt_pk_f32_fp8 must be an IMMEDIATE -> template parameter.
__device__ __forceinline__ unsigned char fp8enc(float v) {
  return (unsigned char)(__builtin_amdgcn_cvt_pk_fp8_f32(v, 0.f, 0u, false) & 0xff);
}
template <bool HI>
__device__ __forceinline__ f32x2 fp8dec2(unsigned int w) {
  return __builtin_amdgcn_cvt_pk_f32_fp8(w, HI);
}

// ---------- Edge dtype detect + zero-row init -------------------------------
__global__ void detect_edges(const int* __restrict__ w, int* __restrict__ flag,
                             unsigned char* __restrict__ p0f,
                             unsigned short* __restrict__ p1u) {
  __shared__ int any;
  if (threadIdx.x == 0) any = 0;
  __syncthreads();
  if (w[2 * threadIdx.x + 1] != 0) any = 1;
  __syncthreads();
  if (threadIdx.x == 0) flag[0] = any ? 0 : 1;  // 1 => int64 layout
  const int t = threadIdx.x;
  if (t < 16) ((unsigned int*)p0f)[(size_t)N_NODES * 16 + t] = 0;  // 64B zero row
  if (t < OUT_DIM) p1u[(size_t)N_NODES * OUT_DIM + t] = 0;  // aggc1 zero row
}

// ---------- Weight convert: B0 fp16 [128n][128k], B1 bf16 [64n][64k] --------
__global__ __launch_bounds__(256) void convW(
    const float* __restrict__ Wn0, const float* __restrict__ Ws0,
    const float* __restrict__ Wn1, const float* __restrict__ Ws1,
    _Float16* __restrict__ B0f, unsigned short* __restrict__ B1u) {
  const int i = blockIdx.x * 256 + threadIdx.x;
  if (i < 128 * 128) {
    const int n = i >> 7, k = i & 127;
    const float w = (n < 64) ? Wn0[k * 64 + n] : Ws0[k * 64 + (n - 64)];
    B0f[i] = (_Float16)w;
  } else if (i < 128 * 128 + 64 * 64) {
    const int j = i - 128 * 128;
    const int n = j >> 6, k = j & 63;
    const float w = (n < 32) ? Wn1[k * 32 + n] : Ws1[k * 32 + (n - 32)];
    B1u[j] = bf16rne(w);
  }
}

// ---------- gemm0 body: 64 rows x 64 cols, one column-group -----------------
__device__ __forceinline__ void gemm0_body(
    int rowblk, int colgrp, int tid, _Float16* lb,
    const float* __restrict__ x, const _Float16* __restrict__ B0f,
    const float* __restrict__ b0, unsigned char* __restrict__ p0f,
    unsigned short* __restrict__ s0bu) {
  const int lane = tid & 63;
  const int wave = tid >> 6;
  const int rowbase = rowblk * 64 + wave * 16;
  const int arow = rowbase + (lane & 15);
  const int rclamp = (arow < N_NODES) ? arow : 0;
  const int ko = (lane >> 4) << 3;  // 0,8,16,24

  float av[32];
  {
    const float* ax = x + (size_t)rclamp * IN_DIM + ko;
#pragma unroll
    for (int ks = 0; ks < 4; ++ks) {
      *(float4*)&av[ks * 8] = *(const float4*)(ax + ks * 32);
      *(float4*)&av[ks * 8 + 4] = *(const float4*)(ax + ks * 32 + 4);
    }
  }
  {
    const uint4* gsrc = (const uint4*)(B0f + (colgrp << 13));  // 64*128 halfs
    for (int i = tid; i < 1024; i += 256) {
      const int o = i << 4;
      const int sw = o ^ (((o >> 8) & 7) << 4);
      *(uint4*)((char*)lb + sw) = gsrc[i];
    }
  }
  __syncthreads();

  half8 ah[4];
#pragma unroll
  for (int ks = 0; ks < 4; ++ks) {
#pragma unroll
    for (int j = 0; j < 8; ++j) ah[ks][j] = (_Float16)av[ks * 8 + j];
  }

  f32x4 acc[4];
#pragma unroll
  for (int ct = 0; ct < 4; ++ct) acc[ct] = (f32x4){0.f, 0.f, 0.f, 0.f};

#pragma unroll
  for (int ks = 0; ks < 4; ++ks) {
    const int kb = ks * 64 + (ko << 1);
#pragma unroll
    for (int ct = 0; ct < 4; ++ct) {
      const int n = ct * 16 + (lane & 15);
      const int boff = (n << 8) + kb;
      const int sb = boff ^ (((boff >> 8) & 7) << 4);
      const half8 bv = *(const half8*)((const char*)lb + sb);
      acc[ct] = __builtin_amdgcn_mfma_f32_16x16x32_f16(ah[ks], bv, acc[ct], 0, 0, 0);
    }
  }
  const int rb4 = rowbase + ((lane >> 4) << 2);
  const int cc = lane & 15;
  if (colgrp == 0) {  // -> p0f (fp8 e4m3)
#pragma unroll
    for (int ct = 0; ct < 4; ++ct) {
#pragma unroll
      for (int j = 0; j < 4; ++j) {
        const int r = rb4 + j;
        if (r < N_NODES) p0f[(size_t)r * HID + ct * 16 + cc] = fp8enc(acc[ct][j]);
      }
    }
  } else {  // -> s0bu (bf16 + bias)
#pragma unroll
    for (int ct = 0; ct < 4; ++ct) {
      const float bias = b0[ct * 16 + cc];
#pragma unroll
      for (int j = 0; j < 4; ++j) {
        const int r = rb4 + j;
        if (r < N_NODES)
          s0bu[(size_t)r * HID + ct * 16 + cc] = bf16rne(acc[ct][j] + bias);
      }
    }
  }
}

// ---------- fuseA: part_count (blocks 0..499) || gemm0 colgrp0 --------------
__global__ __launch_bounds__(256) void fuseA(
    const float* __restrict__ x, const _Float16* __restrict__ B0f,
    const float* __restrict__ b0,
    unsigned char* __restrict__ p0f, unsigned short* __restrict__ s0bu,
    const int* __restrict__ w, const int* __restrict__ flag,
    int* __restrict__ blkbase) {
  __shared__ _Float16 lb[64 * 128];  // 16 KB (pc path: int hist scratch)
  const int tid = threadIdx.x;

  if (blockIdx.x < NPBLK) {
    int* h = (int*)lb;
    const int b = blockIdx.x;
    for (int i = tid; i < NBKT; i += 256) h[i] = 0;
    __syncthreads();
    const int i64 = flag[0];
    const int pEnd = (b + 1) * PAIRS_PER_BLK;
    for (int p = b * PAIRS_PER_BLK + tid; p < pEnd; p += 256) {
      int d0, d1;
      if (i64) {
        const int4 vd = *(const int4*)(w + 2 * (size_t)N_EDGES + 4 * (size_t)p);
        d0 = vd.x; d1 = vd.z;
      } else {
        const int2 vd = *(const int2*)(w + (size_t)N_EDGES + 2 * (size_t)p);
        d0 = vd.x; d1 = vd.y;
      }
      atomicAdd(&h[d0 >> 7], 1);
      atomicAdd(&h[d1 >> 7], 1);
    }
    __syncthreads();
    for (int i = tid; i < NBKT; i += 256)
      blkbase[(size_t)b * NBKT + i] = h[i];  // plain coalesced store
    return;
  }
  gemm0_body(blockIdx.x - NPBLK, 0, tid, lb, x, B0f, b0, p0f, s0bu);
}

// ---------- bscan: per-bucket cross-block exclusive scan (782 blocks) -------
__global__ __launch_bounds__(256) void bscan(int* __restrict__ blkbase,
                                             int* __restrict__ gcount) {
  __shared__ int lds[256];
  const int i = blockIdx.x;  // bucket
  const int t = threadIdx.x;
  const int v0 = (t < NPBLK) ? blkbase[(size_t)t * NBKT + i] : 0;
  const int v1 = (t + 256 < NPBLK) ? blkbase[(size_t)(t + 256) * NBKT + i] : 0;
  const int s = v0 + v1;
  lds[t] = s;
  __syncthreads();
  for (int o = 1; o < 256; o <<= 1) {
    const int val = (t >= o) ? lds[t - o] : 0;
    __syncthreads();
    lds[t] += val;
    __syncthreads();
  }
  const int run = lds[t] - s;
  if (t == 255) gcount[i] = lds[255];
  if (t < NPBLK) blkbase[(size_t)t * NBKT + i] = run;
  if (t + 256 < NPBLK) blkbase[(size_t)(t + 256) * NBKT + i] = run + v0;
}

// ---------- Phase B: single-block exclusive scan of 782 bucket counts -------
__global__ __launch_bounds__(256) void part_scan(
    const int* __restrict__ gcount, int* __restrict__ gbase) {
  __shared__ int lds[256];
  const int t = threadIdx.x;
  int v[4];
  int s = 0;
#pragma unroll
  for (int j = 0; j < 4; ++j) {
    const int idx = t * 4 + j;
    v[j] = (idx < NBKT) ? gcount[idx] : 0;
    s += v[j];
  }
  lds[t] = s;
  __syncthreads();
  for (int o = 1; o < 256; o <<= 1) {
    const int val = (t >= o) ? lds[t - o] : 0;
    __syncthreads();
    lds[t] += val;
    __syncthreads();
  }
  int run = lds[t] - s;
#pragma unroll
  for (int j = 0; j < 4; ++j) {
    const int idx = t * 4 + j;
    if (idx < NBKT) gbase[idx] = run;
    run += v[j];
  }
}

// ---------- fuseB: part_scatter (blocks 0..499) || gemm0 colgrp1 ------------
// pe[e] = src | (localdst << 17)   (src < 2^17, localdst < 128)
__global__ __launch_bounds__(256) void fuseB(
    const float* __restrict__ x, const _Float16* __restrict__ B0f,
    const float* __restrict__ b0,
    unsigned char* __restrict__ p0f, unsigned short* __restrict__ s0bu,
    const int* __restrict__ w, const int* __restrict__ flag,
    const int* __restrict__ gbase, const int* __restrict__ blkbase,
    int* __restrict__ pe) {
  __shared__ _Float16 lb[64 * 128];  // 16 KB (scatter path: cur[] scratch)
  const int tid = threadIdx.x;

  if (blockIdx.x < NPBLK) {
    int* cur = (int*)lb;
    const int t = tid, b = blockIdx.x;
    for (int i = t; i < NBKT; i += 256)
      cur[i] = gbase[i] + blkbase[(size_t)b * NBKT + i];
    __syncthreads();
    const int i64 = flag[0];
    const int pEnd = (b + 1) * PAIRS_PER_BLK;
    for (int p = b * PAIRS_PER_BLK + t; p < pEnd; p += 256) {
      int s0, s1, d0, d1;
      if (i64) {
        const int4 vs = *(const int4*)(w + 4 * (size_t)p);
        const int4 vd = *(const int4*)(w + 2 * (size_t)N_EDGES + 4 * (size_t)p);
        s0 = vs.x; s1 = vs.z;
        d0 = vd.x; d1 = vd.z;
      } else {
        const int2 vs = *(const int2*)(w + 2 * (size_t)p);
        const int2 vd = *(const int2*)(w + (size_t)N_EDGES + 2 * (size_t)p);
        s0 = vs.x; s1 = vs.y;
        d0 = vd.x; d1 = vd.y;
      }
      const int sl0 = atomicAdd(&cur[d0 >> 7], 1);
      pe[sl0] = s0 | ((d0 & 127) << 17);
      const int sl1 = atomicAdd(&cur[d1 >> 7], 1);
      pe[sl1] = s1 | ((d1 & 127) << 17);
    }
    return;
  }
  gemm0_body(blockIdx.x - NPBLK, 1, tid, lb, x, B0f, b0, p0f, s0bu);
}

// ---------- Phase D: per-bucket CSR build, padded to x8 with zero-row -------
__global__ __launch_bounds__(256) void bucket_csr(
    const int* __restrict__ pe, const int* __restrict__ gbase,
    const int* __restrict__ gcount, int* __restrict__ deg,
    int* __restrict__ off, int* __restrict__ sortedSrc) {
  __shared__ int ldeg[128];
  __shared__ int loff[128];
  __shared__ int lcur[128];
  const int t = threadIdx.x;
  const int bkt = blockIdx.x;
  const int nbase = bkt << 7;
  const int ebase = gbase[bkt];
  const int cnt = gcount[bkt];
  const int outbase = ebase + PADCAP * bkt;
  if (t < 128) ldeg[t] = 0;
  __syncthreads();
  for (int e = t; e < cnt; e += 256) {
    const int pv = pe[ebase + e];
    atomicAdd(&ldeg[(pv >> 17) & 127], 1);
  }
  __syncthreads();
  if (t < 128) loff[t] = (ldeg[t] + 7) & ~7;  // padded degree (x8)
  __syncthreads();
  for (int o = 1; o < 128; o <<= 1) {
    int v = 0;
    if (t >= o && t < 128) v = loff[t - o];
    __syncthreads();
    if (t < 128) loff[t] += v;
    __syncthreads();
  }
  if (t < 128) {
    const int pdeg = (ldeg[t] + 7) & ~7;
    const int ex = loff[t] - pdeg;
    lcur[t] = ex;
    const int n = nbase + t;
    if (n < N_NODES) {
      deg[n] = ldeg[t];
      off[n] = outbase + ex;
    }
  }
  __syncthreads();
  for (int e = t; e < cnt; e += 256) {
    const int pv = pe[ebase + e];
    const int ld = (pv >> 17) & 127;
    const int p = atomicAdd(&lcur[ld], 1);
    sortedSrc[outbase + p] = pv & 0x1FFFF;
  }
  __syncthreads();
  if (t < 128) {
    const int pdeg = (ldeg[t] + 7) & ~7;
    const int ex = loff[t] - pdeg;
    for (int q = ldeg[t]; q < pdeg; ++q)
      sortedSrc[outbase + ex + q] = N_NODES;  // zero row
  }
}

// ------- Layer 1 bf16 MFMA GEMM: [p1 | s1b] = h1 @ [Wn1 | Ws1] (+b1) --------
__global__ __launch_bounds__(256) void gemm1(
    const unsigned short* __restrict__ h1u, const unsigned short* __restrict__ B1u,
    const float* __restrict__ b1,
    unsigned short* __restrict__ p1u, unsigned short* __restrict__ s1bu) {
  __shared__ unsigned short lb[64 * 64];  // 8 KB
  const int tid = threadIdx.x;
  const int lane = tid & 63;
  const int wave = tid >> 6;
  const int rowbase = blockIdx.x * 64 + wave * 16;
  const int arow = rowbase + (lane & 15);
  const int rclamp = (arow < N_NODES) ? arow : 0;
  const int ko = (lane >> 4) << 3;

  short8 ah[2];
  {
    const unsigned short* ax = h1u + (size_t)rclamp * HID + ko;
    ah[0] = *(const short8*)ax;
    ah[1] = *(const short8*)(ax + 32);
  }
  {
    const uint4* gb = (const uint4*)B1u;
    for (int i = tid; i < 512; i += 256) {
      const int o = i << 4;
      const int sw = o ^ (((o >> 7) & 7) << 4);
      *(uint4*)((char*)lb + sw) = gb[i];
    }
  }
  __syncthreads();

  f32x4 acc[4];
#pragma unroll
  for (int ct = 0; ct < 4; ++ct) acc[ct] = (f32x4){0.f, 0.f, 0.f, 0.f};

#pragma unroll
  for (int ks = 0; ks < 2; ++ks) {
    const int kb = ks * 64 + (ko << 1);
#pragma unroll
    for (int ct = 0; ct < 4; ++ct) {
      const int n = ct * 16 + (lane & 15);
      const int boff = (n << 7) + kb;
      const int sb = boff ^ (((boff >> 7) & 7) << 4);
      const short8 bv = *(const short8*)((const char*)lb + sb);
      acc[ct] = __builtin_amdgcn_mfma_f32_16x16x32_bf16(ah[ks], bv, acc[ct], 0, 0, 0);
    }
  }
  const int rb4 = rowbase + ((lane >> 4) << 2);
  const int cc = lane & 15;
#pragma unroll
  for (int ct = 0; ct < 2; ++ct) {  // -> p1 (bf16)
#pragma unroll
    for (int j = 0; j < 4; ++j) {
      const int r = rb4 + j;
      if (r < N_NODES) p1u[(size_t)r * OUT_DIM + ct * 16 + cc] = bf16rne(acc[ct][j]);
    }
  }
#pragma unroll
  for (int ct = 2; ct < 4; ++ct) {  // -> s1bu (bf16 + bias)
#pragma unroll
    for (int j = 0; j < 4; ++j) {
      const int r = rb4 + j;
      if (r < N_NODES)
        s1bu[(size_t)r * OUT_DIM + (ct - 2) * 16 + cc] =
            bf16rne(acc[ct][j] + b1[(ct - 2) * 16 + cc]);
    }
  }
}

// ------- Fused layer-0 aggregate (fp8 gather) + mean + LN + ReLU -> h1u -----
// 2 nodes/wave. lane = [h:1][grp:3][sl:2]; row = 64B fp8 = ONE cache line.
__global__ __launch_bounds__(256) void aggc0(
    const int* __restrict__ sortedSrc, const int* __restrict__ off,
    const int* __restrict__ deg, const unsigned char* __restrict__ p0f,
    const unsigned short* __restrict__ s0bu, const float* __restrict__ g,
    const float* __restrict__ be, unsigned short* __restrict__ h1u) {
  const int lane = threadIdx.x & 63;
  const int h = lane >> 5;          // node half
  const int grp = (lane >> 2) & 7;  // 8 edge groups
  const int sl = lane & 3;          // 4 slices of 16 feats
  const int i = blockIdx.x * 8 + ((threadIdx.x >> 6) << 1) + h;
  const int st = off[i];
  const int dg = deg[i];
  const int dgp = (dg + 7) & ~7;
  const int dgmaxp = max(dgp, __shfl_xor(dgp, 32));
  float acc[16];
#pragma unroll
  for (int f = 0; f < 16; ++f) acc[f] = 0.f;

  for (int base = 0; base < dgmaxp; base += 32) {
    const int cntp = dgp - base;
    const int l5 = lane & 31;
    const int idx = (l5 < cntp) ? sortedSrc[st + base + l5] : N_NODES;
    const int cm = min(32, dgmaxp - base);  // multiple of 8
    for (int j = 0; j * 8 < cm; ++j) {
      const int e = j * 8 + grp;
      const int srcn = __shfl(idx, (h << 5) | e);
      const uint4 q = *(const uint4*)(p0f + (size_t)srcn * HID + sl * 16);
      f32x2 t;
      t = fp8dec2<false>(q.x); acc[0] += t.x;  acc[1] += t.y;
      t = fp8dec2<true>(q.x);  acc[2] += t.x;  acc[3] += t.y;
      t = fp8dec2<false>(q.y); acc[4] += t.x;  acc[5] += t.y;
      t = fp8dec2<true>(q.y);  acc[6] += t.x;  acc[7] += t.y;
      t = fp8dec2<false>(q.z); acc[8] += t.x;  acc[9] += t.y;
      t = fp8dec2<true>(q.z);  acc[10] += t.x; acc[11] += t.y;
      t = fp8dec2<false>(q.w); acc[12] += t.x; acc[13] += t.y;
      t = fp8dec2<true>(q.w);  acc[14] += t.x; acc[15] += t.y;
    }
  }
  // fold edge groups (xor over lane bits 2,3,4 — stays within node half)
#pragma unroll
  for (int mk = 4; mk < 32; mk <<= 1) {
#pragma unroll
    for (int f = 0; f < 16; ++f) acc[f] += __shfl_xor(acc[f], mk);
  }
  const float inv = 1.0f / fmaxf((float)dg, 1.0f);
  float z[16];
  const uint4 sb0 = *(const uint4*)(s0bu + (size_t)i * HID + sl * 16);
  const uint4 sb1 = *(const uint4*)(s0bu + (size_t)i * HID + sl * 16 + 8);
  z[0] = uflo(sb0.x) + acc[0] * inv;  z[1] = ufhi(sb0.x) + acc[1] * inv;
  z[2] = uflo(sb0.y) + acc[2] * inv;  z[3] = ufhi(sb0.y) + acc[3] * inv;
  z[4] = uflo(sb0.z) + acc[4] * inv;  z[5] = ufhi(sb0.z) + acc[5] * inv;
  z[6] = uflo(sb0.w) + acc[6] * inv;  z[7] = ufhi(sb0.w) + acc[7] * inv;
  z[8] = uflo(sb1.x) + acc[8] * inv;  z[9] = ufhi(sb1.x) + acc[9] * inv;
  z[10] = uflo(sb1.y) + acc[10] * inv; z[11] = ufhi(sb1.y) + acc[11] * inv;
  z[12] = uflo(sb1.z) + acc[12] * inv; z[13] = ufhi(sb1.z) + acc[13] * inv;
  z[14] = uflo(sb1.w) + acc[14] * inv; z[15] = ufhi(sb1.w) + acc[15] * inv;
  float pm = 0.f;
#pragma unroll
  for (int f = 0; f < 16; ++f) pm += z[f];
#pragma unroll
  for (int mk = 1; mk < 4; mk <<= 1) pm += __shfl_xor(pm, mk);
  const float mean = pm * (1.0f / 64.0f);
  float pv = 0.f;
#pragma unroll
  for (int f = 0; f < 16; ++f) {
    z[f] -= mean;
    pv += z[f] * z[f];
  }
#pragma unroll
  for (int mk = 1; mk < 4; mk <<= 1) pv += __shfl_xor(pv, mk);
  const float rstd = rsqrtf(pv * (1.0f / 64.0f) + LN_EPS);
  if (grp == 0) {
    float o16[16];
#pragma unroll
    for (int f = 0; f < 16; ++f) {
      const float gv = g[sl * 16 + f];
      const float bv = be[sl * 16 + f];
      o16[f] = fmaxf(z[f] * rstd * gv + bv, 0.f);
    }
    uint4 ov0, ov1;
    ov0.x = pk(o16[0], o16[1]);   ov0.y = pk(o16[2], o16[3]);
    ov0.z = pk(o16[4], o16[5]);   ov0.w = pk(o16[6], o16[7]);
    ov1.x = pk(o16[8], o16[9]);   ov1.y = pk(o16[10], o16[11]);
    ov1.z = pk(o16[12], o16[13]); ov1.w = pk(o16[14], o16[15]);
    *(uint4*)(h1u + (size_t)i * HID + sl * 16) = ov0;
    *(uint4*)(h1u + (size_t)i * HID + sl * 16 + 8) = ov1;
  }
}

// ------- Fused layer-1 aggregate + mean + LN + ReLU -> out (4 nodes/wave) ---
// (bf16 p1u; pad-to-8 CSR is a superset of the x4 reads used here.)
__global__ __launch_bounds__(256) void aggc1(
    const int* __restrict__ sortedSrc, const int* __restrict__ off,
    const int* __restrict__ deg, const unsigned short* __restrict__ p1u,
    const unsigned short* __restrict__ s1bu, const float* __restrict__ g,
    const float* __restrict__ be, float* __restrict__ out) {
  const int lane = threadIdx.x & 63;
  const int q4 = lane >> 4;         // node quarter
  const int grp = (lane >> 2) & 3;  // 4 edge groups
  const int sl = lane & 3;          // 4 feature slices
  const int i = blockIdx.x * 16 + ((threadIdx.x >> 6) << 2) + q4;
  const int st = off[i];
  const int dg = deg[i];
  const int dgp = (dg + 3) & ~3;
  int dm = max(dgp, __shfl_xor(dgp, 16));
  const int dgmaxp = max(dm, __shfl_xor(dm, 32));
  float acc[8];
#pragma unroll
  for (int f = 0; f < 8; ++f) acc[f] = 0.f;

  for (int base = 0; base < dgmaxp; base += 16) {
    const int cntp = dgp - base;
    const int l4 = lane & 15;
    const int idx = (l4 < cntp) ? sortedSrc[st + base + l4] : N_NODES;
    const int cm = min(16, dgmaxp - base);  // multiple of 4
    for (int j = 0; j * 4 < cm; ++j) {
      const int e = j * 4 + grp;
      const int srcn = __shfl(idx, (q4 << 4) | e);
      const uint4 qv = *(const uint4*)(p1u + (size_t)srcn * OUT_DIM + sl * 8);
      acc[0] += uflo(qv.x); acc[1] += ufhi(qv.x);
      acc[2] += uflo(qv.y); acc[3] += ufhi(qv.y);
      acc[4] += uflo(qv.z); acc[5] += ufhi(qv.z);
      acc[6] += uflo(qv.w); acc[7] += ufhi(qv.w);
    }
  }
  // fold edge groups (xor over lane bits 2,3 — stays within node quarter)
#pragma unroll
  for (int mk = 4; mk < 16; mk <<= 1) {
#pragma unroll
    for (int f = 0; f < 8; ++f) acc[f] += __shfl_xor(acc[f], mk);
  }
  const float inv = 1.0f / fmaxf((float)dg, 1.0f);
  float z[8];
  const uint4 sbv = *(const uint4*)(s1bu + (size_t)i * OUT_DIM + sl * 8);
  z[0] = uflo(sbv.x) + acc[0] * inv; z[1] = ufhi(sbv.x) + acc[1] * inv;
  z[2] = uflo(sbv.y) + acc[2] * inv; z[3] = ufhi(sbv.y) + acc[3] * inv;
  z[4] = uflo(sbv.z) + acc[4] * inv; z[5] = ufhi(sbv.z) + acc[5] * inv;
  z[6] = uflo(sbv.w) + acc[6] * inv; z[7] = ufhi(sbv.w) + acc[7] * inv;
  float pm = 0.f;
#pragma unroll
  for (int f = 0; f < 8; ++f) pm += z[f];
#pragma unroll
  for (int mk = 1; mk < 4; mk <<= 1) pm += __shfl_xor(pm, mk);
  const float mean = pm * (1.0f / 32.0f);
  float pv = 0.f;
#pragma unroll
  for (int f = 0; f < 8; ++f) {
    z[f] -= mean;
    pv += z[f] * z[f];
  }
#pragma unroll
  for (int mk = 1; mk < 4; mk <<= 1) pv += __shfl_xor(pv, mk);
  const float rstd = rsqrtf(pv * (1.0f / 32.0f) + LN_EPS);
  if (grp == 0) {
    const float4 gv0 = *(const float4*)(g + sl * 8);
    const float4 gv1 = *(const float4*)(g + sl * 8 + 4);
    const float4 bv0 = *(const float4*)(be + sl * 8);
    const float4 bv1 = *(const float4*)(be + sl * 8 + 4);
    float4 o0, o1;
    o0.x = fmaxf(z[0] * rstd * gv0.x + bv0.x, 0.f);
    o0.y = fmaxf(z[1] * rstd * gv0.y + bv0.y, 0.f);
    o0.z = fmaxf(z[2] * rstd * gv0.z + bv0.z, 0.f);
    o0.w = fmaxf(z[3] * rstd * gv0.w + bv0.w, 0.f);
    o1.x = fmaxf(z[4] * rstd * gv1.x + bv1.x, 0.f);
    o1.y = fmaxf(z[5] * rstd * gv1.y + bv1.y, 0.f);
    o1.z = fmaxf(z[6] * rstd * gv1.z + bv1.z, 0.f);
    o1.w = fmaxf(z[7] * rstd * gv1.w + bv1.w, 0.f);
    *(float4*)(out + (size_t)i * OUT_DIM + sl * 8) = o0;
    *(float4*)(out + (size_t)i * OUT_DIM + sl * 8 + 4) = o1;
  }
}

extern "C" void kernel_launch(void* const* d_in, const int* in_sizes, int n_in,
                              void* d_out, int out_size, void* d_ws, size_t ws_size,
                              hipStream_t stream) {
  const float* x       = (const float*)d_in[0];
  const int*   edges   = (const int*)d_in[1];
  const float* Wself0  = (const float*)d_in[2];
  const float* Wneigh0 = (const float*)d_in[3];
  const float* b0      = (const float*)d_in[4];
  const float* g0      = (const float*)d_in[5];
  const float* be0     = (const float*)d_in[6];
  const float* Wself1  = (const float*)d_in[7];
  const float* Wneigh1 = (const float*)d_in[8];
  const float* b1      = (const float*)d_in[9];
  const float* g1      = (const float*)d_in[10];
  const float* be1     = (const float*)d_in[11];

  // ---- 256-byte-aligned workspace carve-out ----
  char* base = (char*)d_ws;
  size_t o = 0;
  auto carve = [&](size_t bytes) {
    char* p = base + o;
    o += (bytes + 255) & ~(size_t)255;
    return p;
  };
  int* flag      = (int*)carve(64 * 4);
  int* gcount    = (int*)carve(1024 * 4);
  int* gbase     = (int*)carve(1024 * 4);
  int* blkbase   = (int*)carve((size_t)NPBLK * NBKT * 4);
  int* deg       = (int*)carve((size_t)N_NODES * 4);
  int* off       = (int*)carve((size_t)N_NODES * 4);
  int* sortedSrc = (int*)carve(2400000 * 4);  // 1.6M + PADCAP*NBKT (x8 pad)
  int* pe        = (int*)carve(6500000);      // 1.62M ints; later p1u overlay
  _Float16* B0f  = (_Float16*)carve(128 * 128 * 2);
  unsigned short* B1u = (unsigned short*)carve(64 * 64 * 2);
  unsigned char* p0f = (unsigned char*)carve(((size_t)N_NODES + 4) * HID);  // fp8
  unsigned short* s0bu = (unsigned short*)carve(((size_t)N_NODES + 2) * HID * 2);
  unsigned short* h1u = (unsigned short*)carve(((size_t)N_NODES + 2) * HID * 2);
  unsigned short* p1u = (unsigned short*)pe;   // overlay (pe dead after csr)
  unsigned short* s1bu = s0bu;                 // overlay (s0bu dead after aggc0)

  detect_edges<<<1, 256, 0, stream>>>(edges, flag, p0f, p1u);
  convW<<<80, 256, 0, stream>>>(Wneigh0, Wself0, Wneigh1, Wself1, B0f, B1u);
  fuseA<<<NPBLK + G0T, 256, 0, stream>>>(x, B0f, b0, p0f, s0bu,
                                         edges, flag, blkbase);
  bscan<<<NBKT, 256, 0, stream>>>(blkbase, gcount);
  part_scan<<<1, 256, 0, stream>>>(gcount, gbase);
  fuseB<<<NPBLK + G0T, 256, 0, stream>>>(x, B0f, b0, p0f, s0bu,
                                         edges, flag, gbase, blkbase, pe);
  bucket_csr<<<NBKT, 256, 0, stream>>>(pe, gbase, gcount, deg, off, sortedSrc);

  aggc0<<<N_NODES / 8, 256, 0, stream>>>(sortedSrc, off, deg, p0f, s0bu,
                                         g0, be0, h1u);
  gemm1<<<(N_NODES + 63) / 64, 256, 0, stream>>>(h1u, B1u, b1, p1u, s1bu);
  aggc1<<<N_NODES / 16, 256, 0, stream>>>(sortedSrc, off, deg, p1u, s1bu,
                                          g1, be1, (float*)d_out);
}

// Round 18
// 147.179 us; speedup vs baseline: 1.0357x; 1.0357x over previous
//
#include <hip/hip_runtime.h>
#include <hip/hip_bf16.h>

#define N_NODES 100000
#define N_EDGES 1600000
#define IN_DIM 128
#define HID 64
#define OUT_DIM 32
#define LN_EPS 1e-5f
#define NBKT 782            // ceil(100000/128) coarse buckets (128 nodes each)
#define NPBLK 500           // partition blocks
#define PAIRS_PER_BLK 1600  // 500*1600*2 = 1.6M edges
#define G0T 1563            // gemm0 row-tiles: ceil(100000/64)
#define PADCAP 384          // max padding per bucket (128 nodes * 3, pad-to-4)

typedef __attribute__((ext_vector_type(8))) _Float16 half8;
typedef __attribute__((ext_vector_type(8))) short short8;
typedef __attribute__((ext_vector_type(4))) float f32x4;

__device__ __forceinline__ float uflo(unsigned int u) {
  return __uint_as_float(u << 16);
}
__device__ __forceinline__ float ufhi(unsigned int u) {
  return __uint_as_float(u & 0xffff0000u);
}
__device__ __forceinline__ unsigned short bf16rne(float f) {
  unsigned int u = __float_as_uint(f);
  unsigned int r = u + 0x7fffu + ((u >> 16) & 1u);
  return (unsigned short)(r >> 16);
}
__device__ __forceinline__ unsigned int pk(float lo, float hi) {
  return (unsigned int)bf16rne(lo) | ((unsigned int)bf16rne(hi) << 16);
}

// ---------- Edge dtype detect + zero-row init -------------------------------
__global__ void detect_edges(const int* __restrict__ w, int* __restrict__ flag,
                             unsigned short* __restrict__ p0u,
                             unsigned short* __restrict__ p1u) {
  __shared__ int any;
  if (threadIdx.x == 0) any = 0;
  __syncthreads();
  if (w[2 * threadIdx.x + 1] != 0) any = 1;
  __syncthreads();
  if (threadIdx.x == 0) flag[0] = any ? 0 : 1;  // 1 => int64 layout
  const int t = threadIdx.x;
  if (t < HID) p0u[(size_t)N_NODES * HID + t] = 0;          // aggc0 zero row
  if (t < OUT_DIM) p1u[(size_t)N_NODES * OUT_DIM + t] = 0;  // aggc1 zero row
}

// ---------- Weight convert: B0 fp16 [128n][128k], B1 bf16 [64n][64k] --------
__global__ __launch_bounds__(256) void convW(
    const float* __restrict__ Wn0, const float* __restrict__ Ws0,
    const float* __restrict__ Wn1, const float* __restrict__ Ws1,
    _Float16* __restrict__ B0f, unsigned short* __restrict__ B1u) {
  const int i = blockIdx.x * 256 + threadIdx.x;
  if (i < 128 * 128) {
    const int n = i >> 7, k = i & 127;
    const float w = (n < 64) ? Wn0[k * 64 + n] : Ws0[k * 64 + (n - 64)];
    B0f[i] = (_Float16)w;
  } else if (i < 128 * 128 + 64 * 64) {
    const int j = i - 128 * 128;
    const int n = j >> 6, k = j & 63;
    const float w = (n < 32) ? Wn1[k * 32 + n] : Ws1[k * 32 + (n - 32)];
    B1u[j] = bf16rne(w);
  }
}

// ---------- gemm0 body: 64 rows x 64 cols, one column-group -----------------
__device__ __forceinline__ void gemm0_body(
    int rowblk, int colgrp, int tid, _Float16* lb,
    const float* __restrict__ x, const _Float16* __restrict__ B0f,
    const float* __restrict__ b0, unsigned short* __restrict__ p0u,
    unsigned short* __restrict__ s0bu) {
  const int lane = tid & 63;
  const int wave = tid >> 6;
  const int rowbase = rowblk * 64 + wave * 16;
  const int arow = rowbase + (lane & 15);
  const int rclamp = (arow < N_NODES) ? arow : 0;
  const int ko = (lane >> 4) << 3;  // 0,8,16,24

  float av[32];
  {
    const float* ax = x + (size_t)rclamp * IN_DIM + ko;
#pragma unroll
    for (int ks = 0; ks < 4; ++ks) {
      *(float4*)&av[ks * 8] = *(const float4*)(ax + ks * 32);
      *(float4*)&av[ks * 8 + 4] = *(const float4*)(ax + ks * 32 + 4);
    }
  }
  {
    const uint4* gsrc = (const uint4*)(B0f + (colgrp << 13));  // 64*128 halfs
    for (int i = tid; i < 1024; i += 256) {
      const int o = i << 4;
      const int sw = o ^ (((o >> 8) & 7) << 4);
      *(uint4*)((char*)lb + sw) = gsrc[i];
    }
  }
  __syncthreads();

  half8 ah[4];
#pragma unroll
  for (int ks = 0; ks < 4; ++ks) {
#pragma unroll
    for (int j = 0; j < 8; ++j) ah[ks][j] = (_Float16)av[ks * 8 + j];
  }

  f32x4 acc[4];
#pragma unroll
  for (int ct = 0; ct < 4; ++ct) acc[ct] = (f32x4){0.f, 0.f, 0.f, 0.f};

#pragma unroll
  for (int ks = 0; ks < 4; ++ks) {
    const int kb = ks * 64 + (ko << 1);
#pragma unroll
    for (int ct = 0; ct < 4; ++ct) {
      const int n = ct * 16 + (lane & 15);
      const int boff = (n << 8) + kb;
      const int sb = boff ^ (((boff >> 8) & 7) << 4);
      const half8 bv = *(const half8*)((const char*)lb + sb);
      acc[ct] = __builtin_amdgcn_mfma_f32_16x16x32_f16(ah[ks], bv, acc[ct], 0, 0, 0);
    }
  }
  const int rb4 = rowbase + ((lane >> 4) << 2);
  const int cc = lane & 15;
  if (colgrp == 0) {  // -> p0u (bf16)
#pragma unroll
    for (int ct = 0; ct < 4; ++ct) {
#pragma unroll
      for (int j = 0; j < 4; ++j) {
        const int r = rb4 + j;
        if (r < N_NODES) p0u[(size_t)r * HID + ct * 16 + cc] = bf16rne(acc[ct][j]);
      }
    }
  } else {  // -> s0bu (bf16 + bias)
#pragma unroll
    for (int ct = 0; ct < 4; ++ct) {
      const float bias = b0[ct * 16 + cc];
#pragma unroll
      for (int j = 0; j < 4; ++j) {
        const int r = rb4 + j;
        if (r < N_NODES)
          s0bu[(size_t)r * HID + ct * 16 + cc] = bf16rne(acc[ct][j] + bias);
      }
    }
  }
}

// ---------- fuseA: part_count (blocks 0..499) || gemm0 colgrp0 --------------
__global__ __launch_bounds__(256) void fuseA(
    const float* __restrict__ x, const _Float16* __restrict__ B0f,
    const float* __restrict__ b0,
    unsigned short* __restrict__ p0u, unsigned short* __restrict__ s0bu,
    const int* __restrict__ w, const int* __restrict__ flag,
    int* __restrict__ blkbase) {
  __shared__ _Float16 lb[64 * 128];  // 16 KB (pc path: int hist scratch)
  const int tid = threadIdx.x;

  if (blockIdx.x < NPBLK) {
    int* h = (int*)lb;
    const int b = blockIdx.x;
    for (int i = tid; i < NBKT; i += 256) h[i] = 0;
    __syncthreads();
    const int i64 = flag[0];
    const int pEnd = (b + 1) * PAIRS_PER_BLK;
    for (int p = b * PAIRS_PER_BLK + tid; p < pEnd; p += 256) {
      int d0, d1;
      if (i64) {
        const int4 vd = *(const int4*)(w + 2 * (size_t)N_EDGES + 4 * (size_t)p);
        d0 = vd.x; d1 = vd.z;
      } else {
        const int2 vd = *(const int2*)(w + (size_t)N_EDGES + 2 * (size_t)p);
        d0 = vd.x; d1 = vd.y;
      }
      atomicAdd(&h[d0 >> 7], 1);
      atomicAdd(&h[d1 >> 7], 1);
    }
    __syncthreads();
    for (int i = tid; i < NBKT; i += 256)
      blkbase[(size_t)b * NBKT + i] = h[i];  // plain coalesced store
    return;
  }
  gemm0_body(blockIdx.x - NPBLK, 0, tid, lb, x, B0f, b0, p0u, s0bu);
}

// ---------- bscan: per-bucket cross-block exclusive scan (782 blocks) -------
__global__ __launch_bounds__(256) void bscan(int* __restrict__ blkbase,
                                             int* __restrict__ gcount) {
  __shared__ int lds[256];
  const int i = blockIdx.x;  // bucket
  const int t = threadIdx.x;
  const int v0 = (t < NPBLK) ? blkbase[(size_t)t * NBKT + i] : 0;
  const int v1 = (t + 256 < NPBLK) ? blkbase[(size_t)(t + 256) * NBKT + i] : 0;
  const int s = v0 + v1;
  lds[t] = s;
  __syncthreads();
  for (int o = 1; o < 256; o <<= 1) {
    const int val = (t >= o) ? lds[t - o] : 0;
    __syncthreads();
    lds[t] += val;
    __syncthreads();
  }
  const int run = lds[t] - s;
  if (t == 255) gcount[i] = lds[255];
  if (t < NPBLK) blkbase[(size_t)t * NBKT + i] = run;
  if (t + 256 < NPBLK) blkbase[(size_t)(t + 256) * NBKT + i] = run + v0;
}

// ---------- Phase B: single-block exclusive scan of 782 bucket counts -------
__global__ __launch_bounds__(256) void part_scan(
    const int* __restrict__ gcount, int* __restrict__ gbase) {
  __shared__ int lds[256];
  const int t = threadIdx.x;
  int v[4];
  int s = 0;
#pragma unroll
  for (int j = 0; j < 4; ++j) {
    const int idx = t * 4 + j;
    v[j] = (idx < NBKT) ? gcount[idx] : 0;
    s += v[j];
  }
  lds[t] = s;
  __syncthreads();
  for (int o = 1; o < 256; o <<= 1) {
    const int val = (t >= o) ? lds[t - o] : 0;
    __syncthreads();
    lds[t] += val;
    __syncthreads();
  }
  int run = lds[t] - s;
#pragma unroll
  for (int j = 0; j < 4; ++j) {
    const int idx = t * 4 + j;
    if (idx < NBKT) gbase[idx] = run;
    run += v[j];
  }
}

// ---------- fuseB: part_scatter (blocks 0..499) || gemm0 colgrp1 ------------
// pe[e] = src | (localdst << 17)   (src < 2^17, localdst < 128)
__global__ __launch_bounds__(256) void fuseB(
    const float* __restrict__ x, const _Float16* __restrict__ B0f,
    const float* __restrict__ b0,
    unsigned short* __restrict__ p0u, unsigned short* __restrict__ s0bu,
    const int* __restrict__ w, const int* __restrict__ flag,
    const int* __restrict__ gbase, const int* __restrict__ blkbase,
    int* __restrict__ pe) {
  __shared__ _Float16 lb[64 * 128];  // 16 KB (scatter path: cur[] scratch)
  const int tid = threadIdx.x;

  if (blockIdx.x < NPBLK) {
    int* cur = (int*)lb;
    const int t = tid, b = blockIdx.x;
    for (int i = t; i < NBKT; i += 256)
      cur[i] = gbase[i] + blkbase[(size_t)b * NBKT + i];
    __syncthreads();
    const int i64 = flag[0];
    const int pEnd = (b + 1) * PAIRS_PER_BLK;
    for (int p = b * PAIRS_PER_BLK + t; p < pEnd; p += 256) {
      int s0, s1, d0, d1;
      if (i64) {
        const int4 vs = *(const int4*)(w + 4 * (size_t)p);
        const int4 vd = *(const int4*)(w + 2 * (size_t)N_EDGES + 4 * (size_t)p);
        s0 = vs.x; s1 = vs.z;
        d0 = vd.x; d1 = vd.z;
      } else {
        const int2 vs = *(const int2*)(w + 2 * (size_t)p);
        const int2 vd = *(const int2*)(w + (size_t)N_EDGES + 2 * (size_t)p);
        s0 = vs.x; s1 = vs.y;
        d0 = vd.x; d1 = vd.y;
      }
      const int sl0 = atomicAdd(&cur[d0 >> 7], 1);
      pe[sl0] = s0 | ((d0 & 127) << 17);
      const int sl1 = atomicAdd(&cur[d1 >> 7], 1);
      pe[sl1] = s1 | ((d1 & 127) << 17);
    }
    return;
  }
  gemm0_body(blockIdx.x - NPBLK, 1, tid, lb, x, B0f, b0, p0u, s0bu);
}

// ---------- Phase D: per-bucket CSR build, padded to x4 with zero-row -------
__global__ __launch_bounds__(256) void bucket_csr(
    const int* __restrict__ pe, const int* __restrict__ gbase,
    const int* __restrict__ gcount, int* __restrict__ deg,
    int* __restrict__ off, int* __restrict__ sortedSrc) {
  __shared__ int ldeg[128];
  __shared__ int loff[128];
  __shared__ int lcur[128];
  const int t = threadIdx.x;
  const int bkt = blockIdx.x;
  const int nbase = bkt << 7;
  const int ebase = gbase[bkt];
  const int cnt = gcount[bkt];
  const int outbase = ebase + PADCAP * bkt;
  if (t < 128) ldeg[t] = 0;
  __syncthreads();
  for (int e = t; e < cnt; e += 256) {
    const int pv = pe[ebase + e];
    atomicAdd(&ldeg[(pv >> 17) & 127], 1);
  }
  __syncthreads();
  if (t < 128) loff[t] = (ldeg[t] + 3) & ~3;  // padded degree
  __syncthreads();
  for (int o = 1; o < 128; o <<= 1) {
    int v = 0;
    if (t >= o && t < 128) v = loff[t - o];
    __syncthreads();
    if (t < 128) loff[t] += v;
    __syncthreads();
  }
  if (t < 128) {
    const int pdeg = (ldeg[t] + 3) & ~3;
    const int ex = loff[t] - pdeg;
    lcur[t] = ex;
    const int n = nbase + t;
    if (n < N_NODES) {
      deg[n] = ldeg[t];
      off[n] = outbase + ex;
    }
  }
  __syncthreads();
  for (int e = t; e < cnt; e += 256) {
    const int pv = pe[ebase + e];
    const int ld = (pv >> 17) & 127;
    const int p = atomicAdd(&lcur[ld], 1);
    sortedSrc[outbase + p] = pv & 0x1FFFF;
  }
  __syncthreads();
  if (t < 128) {
    const int pdeg = (ldeg[t] + 3) & ~3;
    const int ex = loff[t] - pdeg;
    for (int q = ldeg[t]; q < pdeg; ++q)
      sortedSrc[outbase + ex + q] = N_NODES;  // zero row
  }
}

// ------- Layer 1 bf16 MFMA GEMM: [p1 | s1b] = h1 @ [Wn1 | Ws1] (+b1) --------
__global__ __launch_bounds__(256) void gemm1(
    const unsigned short* __restrict__ h1u, const unsigned short* __restrict__ B1u,
    const float* __restrict__ b1,
    unsigned short* __restrict__ p1u, unsigned short* __restrict__ s1bu) {
  __shared__ unsigned short lb[64 * 64];  // 8 KB
  const int tid = threadIdx.x;
  const int lane = tid & 63;
  const int wave = tid >> 6;
  const int rowbase = blockIdx.x * 64 + wave * 16;
  const int arow = rowbase + (lane & 15);
  const int rclamp = (arow < N_NODES) ? arow : 0;
  const int ko = (lane >> 4) << 3;

  short8 ah[2];
  {
    const unsigned short* ax = h1u + (size_t)rclamp * HID + ko;
    ah[0] = *(const short8*)ax;
    ah[1] = *(const short8*)(ax + 32);
  }
  {
    const uint4* gb = (const uint4*)B1u;
    for (int i = tid; i < 512; i += 256) {
      const int o = i << 4;
      const int sw = o ^ (((o >> 7) & 7) << 4);
      *(uint4*)((char*)lb + sw) = gb[i];
    }
  }
  __syncthreads();

  f32x4 acc[4];
#pragma unroll
  for (int ct = 0; ct < 4; ++ct) acc[ct] = (f32x4){0.f, 0.f, 0.f, 0.f};

#pragma unroll
  for (int ks = 0; ks < 2; ++ks) {
    const int kb = ks * 64 + (ko << 1);
#pragma unroll
    for (int ct = 0; ct < 4; ++ct) {
      const int n = ct * 16 + (lane & 15);
      const int boff = (n << 7) + kb;
      const int sb = boff ^ (((boff >> 7) & 7) << 4);
      const short8 bv = *(const short8*)((const char*)lb + sb);
      acc[ct] = __builtin_amdgcn_mfma_f32_16x16x32_bf16(ah[ks], bv, acc[ct], 0, 0, 0);
    }
  }
  const int rb4 = rowbase + ((lane >> 4) << 2);
  const int cc = lane & 15;
#pragma unroll
  for (int ct = 0; ct < 2; ++ct) {  // -> p1 (bf16)
#pragma unroll
    for (int j = 0; j < 4; ++j) {
      const int r = rb4 + j;
      if (r < N_NODES) p1u[(size_t)r * OUT_DIM + ct * 16 + cc] = bf16rne(acc[ct][j]);
    }
  }
#pragma unroll
  for (int ct = 2; ct < 4; ++ct) {  // -> s1bu (bf16 + bias)
#pragma unroll
    for (int j = 0; j < 4; ++j) {
      const int r = rb4 + j;
      if (r < N_NODES)
        s1bu[(size_t)r * OUT_DIM + (ct - 2) * 16 + cc] =
            bf16rne(acc[ct][j] + b1[(ct - 2) * 16 + cc]);
    }
  }
}

// ------- Fused layer-0 aggregate + mean + LN + ReLU -> h1u (2 nodes/wave) ---
// Deep-prefetch gather: 8 independent 16B loads in flight per lane per chunk.
// Masking is data-driven (padding lanes carry the zero-row index).
__global__ __launch_bounds__(256) void aggc0(
    const int* __restrict__ sortedSrc, const int* __restrict__ off,
    const int* __restrict__ deg, const unsigned short* __restrict__ p0u,
    const unsigned short* __restrict__ s0bu, const float* __restrict__ g,
    const float* __restrict__ be, unsigned short* __restrict__ h1u) {
  const int lane = threadIdx.x & 63;
  const int h = lane >> 5;          // node half
  const int grp = (lane >> 3) & 3;  // 4 edge groups
  const int sl = lane & 7;          // 8 feature slices
  const int i = blockIdx.x * 8 + ((threadIdx.x >> 6) << 1) + h;
  const int st = off[i];
  const int dg = deg[i];
  const int dgp = (dg + 3) & ~3;
  const int dgmaxp = max(dgp, __shfl_xor(dgp, 32));
  float acc[8];
#pragma unroll
  for (int f = 0; f < 8; ++f) acc[f] = 0.f;

  for (int base = 0; base < dgmaxp; base += 32) {
    const int cntp = dgp - base;
    const int l5 = lane & 31;
    const int idx = (l5 < cntp) ? sortedSrc[st + base + l5] : N_NODES;
    int srcs[8];
#pragma unroll
    for (int j = 0; j < 8; ++j) srcs[j] = __shfl(idx, (h << 5) | (j * 4 + grp));
    uint4 qs[8];
#pragma unroll
    for (int j = 0; j < 8; ++j)
      qs[j] = *(const uint4*)(p0u + (size_t)srcs[j] * HID + sl * 8);
#pragma unroll
    for (int j = 0; j < 8; ++j) {
      acc[0] += uflo(qs[j].x); acc[1] += ufhi(qs[j].x);
      acc[2] += uflo(qs[j].y); acc[3] += ufhi(qs[j].y);
      acc[4] += uflo(qs[j].z); acc[5] += ufhi(qs[j].z);
      acc[6] += uflo(qs[j].w); acc[7] += ufhi(qs[j].w);
    }
  }
  // fold edge groups (xor over lane bits 3,4 — stays within node half)
#pragma unroll
  for (int mk = 8; mk < 32; mk <<= 1) {
#pragma unroll
    for (int f = 0; f < 8; ++f) acc[f] += __shfl_xor(acc[f], mk);
  }
  const float inv = 1.0f / fmaxf((float)dg, 1.0f);
  float z[8];
  const uint4 sbv = *(const uint4*)(s0bu + (size_t)i * HID + sl * 8);
  z[0] = uflo(sbv.x) + acc[0] * inv; z[1] = ufhi(sbv.x) + acc[1] * inv;
  z[2] = uflo(sbv.y) + acc[2] * inv; z[3] = ufhi(sbv.y) + acc[3] * inv;
  z[4] = uflo(sbv.z) + acc[4] * inv; z[5] = ufhi(sbv.z) + acc[5] * inv;
  z[6] = uflo(sbv.w) + acc[6] * inv; z[7] = ufhi(sbv.w) + acc[7] * inv;
  float pm = 0.f;
#pragma unroll
  for (int f = 0; f < 8; ++f) pm += z[f];
#pragma unroll
  for (int mk = 1; mk < 8; mk <<= 1) pm += __shfl_xor(pm, mk);
  const float mean = pm * (1.0f / 64.0f);
  float pv = 0.f;
#pragma unroll
  for (int f = 0; f < 8; ++f) {
    z[f] -= mean;
    pv += z[f] * z[f];
  }
#pragma unroll
  for (int mk = 1; mk < 8; mk <<= 1) pv += __shfl_xor(pv, mk);
  const float rstd = rsqrtf(pv * (1.0f / 64.0f) + LN_EPS);
  if (grp == 0) {
    const float4 gv0 = *(const float4*)(g + sl * 8);
    const float4 gv1 = *(const float4*)(g + sl * 8 + 4);
    const float4 bv0 = *(const float4*)(be + sl * 8);
    const float4 bv1 = *(const float4*)(be + sl * 8 + 4);
    uint4 ov;
    ov.x = pk(fmaxf(z[0] * rstd * gv0.x + bv0.x, 0.f),
              fmaxf(z[1] * rstd * gv0.y + bv0.y, 0.f));
    ov.y = pk(fmaxf(z[2] * rstd * gv0.z + bv0.z, 0.f),
              fmaxf(z[3] * rstd * gv0.w + bv0.w, 0.f));
    ov.z = pk(fmaxf(z[4] * rstd * gv1.x + bv1.x, 0.f),
              fmaxf(z[5] * rstd * gv1.y + bv1.y, 0.f));
    ov.w = pk(fmaxf(z[6] * rstd * gv1.z + bv1.z, 0.f),
              fmaxf(z[7] * rstd * gv1.w + bv1.w, 0.f));
    *(uint4*)(h1u + (size_t)i * HID + sl * 8) = ov;
  }
}

// ------- Fused layer-1 aggregate + mean + LN + ReLU -> out (4 nodes/wave) ---
// Deep-prefetch gather: 4 independent loads in flight per lane per chunk.
__global__ __launch_bounds__(256) void aggc1(
    const int* __restrict__ sortedSrc, const int* __restrict__ off,
    const int* __restrict__ deg, const unsigned short* __restrict__ p1u,
    const unsigned short* __restrict__ s1bu, const float* __restrict__ g,
    const float* __restrict__ be, float* __restrict__ out) {
  const int lane = threadIdx.x & 63;
  const int q4 = lane >> 4;         // node quarter
  const int grp = (lane >> 2) & 3;  // 4 edge groups
  const int sl = lane & 3;          // 4 feature slices
  const int i = blockIdx.x * 16 + ((threadIdx.x >> 6) << 2) + q4;
  const int st = off[i];
  const int dg = deg[i];
  const int dgp = (dg + 3) & ~3;
  int dm = max(dgp, __shfl_xor(dgp, 16));
  const int dgmaxp = max(dm, __shfl_xor(dm, 32));
  float acc[8];
#pragma unroll
  for (int f = 0; f < 8; ++f) acc[f] = 0.f;

  for (int base = 0; base < dgmaxp; base += 16) {
    const int cntp = dgp - base;
    const int l4 = lane & 15;
    const int idx = (l4 < cntp) ? sortedSrc[st + base + l4] : N_NODES;
    int srcs[4];
#pragma unroll
    for (int j = 0; j < 4; ++j) srcs[j] = __shfl(idx, (q4 << 4) | (j * 4 + grp));
    uint4 qs[4];
#pragma unroll
    for (int j = 0; j < 4; ++j)
      qs[j] = *(const uint4*)(p1u + (size_t)srcs[j] * OUT_DIM + sl * 8);
#pragma unroll
    for (int j = 0; j < 4; ++j) {
      acc[0] += uflo(qs[j].x); acc[1] += ufhi(qs[j].x);
      acc[2] += uflo(qs[j].y); acc[3] += ufhi(qs[j].y);
      acc[4] += uflo(qs[j].z); acc[5] += ufhi(qs[j].z);
      acc[6] += uflo(qs[j].w); acc[7] += ufhi(qs[j].w);
    }
  }
  // fold edge groups (xor over lane bits 2,3 — stays within node quarter)
#pragma unroll
  for (int mk = 4; mk < 16; mk <<= 1) {
#pragma unroll
    for (int f = 0; f < 8; ++f) acc[f] += __shfl_xor(acc[f], mk);
  }
  const float inv = 1.0f / fmaxf((float)dg, 1.0f);
  float z[8];
  const uint4 sbv = *(const uint4*)(s1bu + (size_t)i * OUT_DIM + sl * 8);
  z[0] = uflo(sbv.x) + acc[0] * inv; z[1] = ufhi(sbv.x) + acc[1] * inv;
  z[2] = uflo(sbv.y) + acc[2] * inv; z[3] = ufhi(sbv.y) + acc[3] * inv;
  z[4] = uflo(sbv.z) + acc[4] * inv; z[5] = ufhi(sbv.z) + acc[5] * inv;
  z[6] = uflo(sbv.w) + acc[6] * inv; z[7] = ufhi(sbv.w) + acc[7] * inv;
  float pm = 0.f;
#pragma unroll
  for (int f = 0; f < 8; ++f) pm += z[f];
#pragma unroll
  for (int mk = 1; mk < 4; mk <<= 1) pm += __shfl_xor(pm, mk);
  const float mean = pm * (1.0f / 32.0f);
  float pv = 0.f;
#pragma unroll
  for (int f = 0; f < 8; ++f) {
    z[f] -= mean;
    pv += z[f] * z[f];
  }
#pragma unroll
  for (int mk = 1; mk < 4; mk <<= 1) pv += __shfl_xor(pv, mk);
  const float rstd = rsqrtf(pv * (1.0f / 32.0f) + LN_EPS);
  if (grp == 0) {
    const float4 gv0 = *(const float4*)(g + sl * 8);
    const float4 gv1 = *(const float4*)(g + sl * 8 + 4);
    const float4 bv0 = *(const float4*)(be + sl * 8);
    const float4 bv1 = *(const float4*)(be + sl * 8 + 4);
    float4 o0, o1;
    o0.x = fmaxf(z[0] * rstd * gv0.x + bv0.x, 0.f);
    o0.y = fmaxf(z[1] * rstd * gv0.y + bv0.y, 0.f);
    o0.z = fmaxf(z[2] * rstd * gv0.z + bv0.z, 0.f);
    o0.w = fmaxf(z[3] * rstd * gv0.w + bv0.w, 0.f);
    o1.x = fmaxf(z[4] * rstd * gv1.x + bv1.x, 0.f);
    o1.y = fmaxf(z[5] * rstd * gv1.y + bv1.y, 0.f);
    o1.z = fmaxf(z[6] * rstd * gv1.z + bv1.z, 0.f);
    o1.w = fmaxf(z[7] * rstd * gv1.w + bv1.w, 0.f);
    *(float4*)(out + (size_t)i * OUT_DIM + sl * 8) = o0;
    *(float4*)(out + (size_t)i * OUT_DIM + sl * 8 + 4) = o1;
  }
}

extern "C" void kernel_launch(void* const* d_in, const int* in_sizes, int n_in,
                              void* d_out, int out_size, void* d_ws, size_t ws_size,
                              hipStream_t stream) {
  const float* x       = (const float*)d_in[0];
  const int*   edges   = (const int*)d_in[1];
  const float* Wself0  = (const float*)d_in[2];
  const float* Wneigh0 = (const float*)d_in[3];
  const float* b0      = (const float*)d_in[4];
  const float* g0      = (const float*)d_in[5];
  const float* be0     = (const float*)d_in[6];
  const float* Wself1  = (const float*)d_in[7];
  const float* Wneigh1 = (const float*)d_in[8];
  const float* b1      = (const float*)d_in[9];
  const float* g1      = (const float*)d_in[10];
  const float* be1     = (const float*)d_in[11];

  // ---- 256-byte-aligned workspace carve-out ----
  char* base = (char*)d_ws;
  size_t o = 0;
  auto carve = [&](size_t bytes) {
    char* p = base + o;
    o += (bytes + 255) & ~(size_t)255;
    return p;
  };
  int* flag      = (int*)carve(64 * 4);
  int* gcount    = (int*)carve(1024 * 4);
  int* gbase     = (int*)carve(1024 * 4);
  int* blkbase   = (int*)carve((size_t)NPBLK * NBKT * 4);
  int* deg       = (int*)carve((size_t)N_NODES * 4);
  int* off       = (int*)carve((size_t)N_NODES * 4);
  int* sortedSrc = (int*)carve(1950000 * 4);  // 1.6M + PADCAP*NBKT
  int* pe        = (int*)carve(6500000);      // 1.62M ints; later p1u overlay
  _Float16* B0f  = (_Float16*)carve(128 * 128 * 2);
  unsigned short* B1u = (unsigned short*)carve(64 * 64 * 2);
  unsigned short* p0u = (unsigned short*)carve(((size_t)N_NODES + 2) * HID * 2);
  unsigned short* s0bu = (unsigned short*)carve(((size_t)N_NODES + 2) * HID * 2);
  unsigned short* h1u = (unsigned short*)carve(((size_t)N_NODES + 2) * HID * 2);
  unsigned short* p1u = (unsigned short*)pe;   // overlay (pe dead after csr)
  unsigned short* s1bu = s0bu;                 // overlay (s0bu dead after aggc0)

  detect_edges<<<1, 256, 0, stream>>>(edges, flag, p0u, p1u);
  convW<<<80, 256, 0, stream>>>(Wneigh0, Wself0, Wneigh1, Wself1, B0f, B1u);
  fuseA<<<NPBLK + G0T, 256, 0, stream>>>(x, B0f, b0, p0u, s0bu,
                                         edges, flag, blkbase);
  bscan<<<NBKT, 256, 0, stream>>>(blkbase, gcount);
  part_scan<<<1, 256, 0, stream>>>(gcount, gbase);
  fuseB<<<NPBLK + G0T, 256, 0, stream>>>(x, B0f, b0, p0u, s0bu,
                                         edges, flag, gbase, blkbase, pe);
  bucket_csr<<<NBKT, 256, 0, stream>>>(pe, gbase, gcount, deg, off, sortedSrc);

  aggc0<<<N_NODES / 8, 256, 0, stream>>>(sortedSrc, off, deg, p0u, s0bu,
                                         g0, be0, h1u);
  gemm1<<<(N_NODES + 63) / 64, 256, 0, stream>>>(h1u, B1u, b1, p1u, s1bu);
  aggc1<<<N_NODES / 16, 256, 0, stream>>>(sortedSrc, off, deg, p1u, s1bu,
                                          g1, be1, (float*)d_out);
}

// Round 19
// 146.062 us; speedup vs baseline: 1.0436x; 1.0076x over previous
//
#include <hip/hip_runtime.h>
#include <hip/hip_bf16.h>

#define N_NODES 100000
#define N_EDGES 1600000
#define IN_DIM 128
#define HID 64
#define OUT_DIM 32
#define LN_EPS 1e-5f
#define NBKT 782            // ceil(100000/128) coarse buckets (128 nodes each)
#define NPBLK 500           // partition blocks
#define PAIRS_PER_BLK 1600  // 500*1600*2 = 1.6M edges
#define G0TA 782            // gemm0 row-tiles in fuseA (rows 0..50047)
#define G0TB 781            // gemm0 row-tiles in fuseB (rows 50048..100031)
#define PADCAP 384          // max padding per bucket (128 nodes * 3, pad-to-4)

typedef __attribute__((ext_vector_type(8))) _Float16 half8;
typedef __attribute__((ext_vector_type(8))) short short8;
typedef __attribute__((ext_vector_type(4))) float f32x4;

__device__ __forceinline__ float uflo(unsigned int u) {
  return __uint_as_float(u << 16);
}
__device__ __forceinline__ float ufhi(unsigned int u) {
  return __uint_as_float(u & 0xffff0000u);
}
__device__ __forceinline__ unsigned short bf16rne(float f) {
  unsigned int u = __float_as_uint(f);
  unsigned int r = u + 0x7fffu + ((u >> 16) & 1u);
  return (unsigned short)(r >> 16);
}
__device__ __forceinline__ unsigned int pk(float lo, float hi) {
  return (unsigned int)bf16rne(lo) | ((unsigned int)bf16rne(hi) << 16);
}

// ---------- detect + zero rows + weight convert (merged, 81 blocks) ---------
__global__ __launch_bounds__(256) void detcw(
    const int* __restrict__ w, int* __restrict__ flag,
    const float* __restrict__ Wn0, const float* __restrict__ Ws0,
    const float* __restrict__ Wn1, const float* __restrict__ Ws1,
    _Float16* __restrict__ B0f, unsigned short* __restrict__ B1u,
    unsigned short* __restrict__ p0u, unsigned short* __restrict__ p1u) {
  __shared__ int any;
  if (blockIdx.x == 80) {
    if (threadIdx.x == 0) any = 0;
    __syncthreads();
    if (w[2 * threadIdx.x + 1] != 0) any = 1;
    __syncthreads();
    if (threadIdx.x == 0) flag[0] = any ? 0 : 1;  // 1 => int64 layout
    const int t = threadIdx.x;
    if (t < HID) p0u[(size_t)N_NODES * HID + t] = 0;          // aggc0 zero row
    if (t < OUT_DIM) p1u[(size_t)N_NODES * OUT_DIM + t] = 0;  // aggc1 zero row
    return;
  }
  const int i = blockIdx.x * 256 + threadIdx.x;
  if (i < 128 * 128) {
    const int n = i >> 7, k = i & 127;
    const float wv = (n < 64) ? Wn0[k * 64 + n] : Ws0[k * 64 + (n - 64)];
    B0f[i] = (_Float16)wv;
  } else if (i < 128 * 128 + 64 * 64) {
    const int j = i - 128 * 128;
    const int n = j >> 6, k = j & 63;
    const float wv = (n < 32) ? Wn1[k * 32 + n] : Ws1[k * 32 + (n - 32)];
    B1u[j] = bf16rne(wv);
  }
}

// ---------- gemm0 body: 64 rows x 128 cols (BOTH col groups, 32 KB LDS) -----
// x row-half per fuse kernel -> x read ONCE total (was twice with col-split).
__device__ __forceinline__ void gemm0_body(
    int rowblk, int tid, _Float16* lb,
    const float* __restrict__ x, const _Float16* __restrict__ B0f,
    const float* __restrict__ b0, unsigned short* __restrict__ p0u,
    unsigned short* __restrict__ s0bu) {
  const int lane = tid & 63;
  const int wave = tid >> 6;
  const int rowbase = rowblk * 64 + wave * 16;
  const int arow = rowbase + (lane & 15);
  const int rclamp = (arow < N_NODES) ? arow : 0;
  const int ko = (lane >> 4) << 3;  // 0,8,16,24

  float av[32];
  {
    const float* ax = x + (size_t)rclamp * IN_DIM + ko;
#pragma unroll
    for (int ks = 0; ks < 4; ++ks) {
      *(float4*)&av[ks * 8] = *(const float4*)(ax + ks * 32);
      *(float4*)&av[ks * 8 + 4] = *(const float4*)(ax + ks * 32 + 4);
    }
  }
  {
    const uint4* gsrc = (const uint4*)B0f;  // 128n x 128k halfs
    for (int i = tid; i < 2048; i += 256) {
      const int o = i << 4;
      const int sw = o ^ (((o >> 8) & 7) << 4);
      *(uint4*)((char*)lb + sw) = gsrc[i];
    }
  }
  __syncthreads();

  half8 ah[4];
#pragma unroll
  for (int ks = 0; ks < 4; ++ks) {
#pragma unroll
    for (int j = 0; j < 8; ++j) ah[ks][j] = (_Float16)av[ks * 8 + j];
  }

  f32x4 acc[8];
#pragma unroll
  for (int ct = 0; ct < 8; ++ct) acc[ct] = (f32x4){0.f, 0.f, 0.f, 0.f};

#pragma unroll
  for (int ks = 0; ks < 4; ++ks) {
    const int kb = ks * 64 + (ko << 1);
#pragma unroll
    for (int ct = 0; ct < 8; ++ct) {
      const int n = ct * 16 + (lane & 15);
      const int boff = (n << 8) + kb;
      const int sb = boff ^ (((boff >> 8) & 7) << 4);
      const half8 bv = *(const half8*)((const char*)lb + sb);
      acc[ct] = __builtin_amdgcn_mfma_f32_16x16x32_f16(ah[ks], bv, acc[ct], 0, 0, 0);
    }
  }
  const int rb4 = rowbase + ((lane >> 4) << 2);
  const int cc = lane & 15;
#pragma unroll
  for (int ct = 0; ct < 4; ++ct) {  // cols 0..63 -> p0u (bf16)
#pragma unroll
    for (int j = 0; j < 4; ++j) {
      const int r = rb4 + j;
      if (r < N_NODES) p0u[(size_t)r * HID + ct * 16 + cc] = bf16rne(acc[ct][j]);
    }
  }
#pragma unroll
  for (int ct = 4; ct < 8; ++ct) {  // cols 64..127 -> s0bu (bf16 + bias)
    const float bias = b0[(ct - 4) * 16 + cc];
#pragma unroll
    for (int j = 0; j < 4; ++j) {
      const int r = rb4 + j;
      if (r < N_NODES)
        s0bu[(size_t)r * HID + (ct - 4) * 16 + cc] = bf16rne(acc[ct][j] + bias);
    }
  }
}

// ---------- fuseA: part_count (blocks 0..499) || gemm0 rows 0..50047 --------
__global__ __launch_bounds__(256) void fuseA(
    const float* __restrict__ x, const _Float16* __restrict__ B0f,
    const float* __restrict__ b0,
    unsigned short* __restrict__ p0u, unsigned short* __restrict__ s0bu,
    const int* __restrict__ w, const int* __restrict__ flag,
    int* __restrict__ blkbase) {
  __shared__ _Float16 lb[128 * 128];  // 32 KB (pc path: int hist scratch)
  const int tid = threadIdx.x;

  if (blockIdx.x < NPBLK) {
    int* h = (int*)lb;
    const int b = blockIdx.x;
    for (int i = tid; i < NBKT; i += 256) h[i] = 0;
    __syncthreads();
    const int i64 = flag[0];
    const int pEnd = (b + 1) * PAIRS_PER_BLK;
    for (int p = b * PAIRS_PER_BLK + tid; p < pEnd; p += 256) {
      int d0, d1;
      if (i64) {
        const int4 vd = *(const int4*)(w + 2 * (size_t)N_EDGES + 4 * (size_t)p);
        d0 = vd.x; d1 = vd.z;
      } else {
        const int2 vd = *(const int2*)(w + (size_t)N_EDGES + 2 * (size_t)p);
        d0 = vd.x; d1 = vd.y;
      }
      atomicAdd(&h[d0 >> 7], 1);
      atomicAdd(&h[d1 >> 7], 1);
    }
    __syncthreads();
    for (int i = tid; i < NBKT; i += 256)
      blkbase[(size_t)b * NBKT + i] = h[i];  // plain coalesced store
    return;
  }
  gemm0_body(blockIdx.x - NPBLK, tid, lb, x, B0f, b0, p0u, s0bu);
}

// ---------- bscan: per-bucket cross-block exclusive scan (782 blocks) -------
__global__ __launch_bounds__(256) void bscan(int* __restrict__ blkbase,
                                             int* __restrict__ gcount) {
  __shared__ int lds[256];
  const int i = blockIdx.x;  // bucket
  const int t = threadIdx.x;
  const int v0 = (t < NPBLK) ? blkbase[(size_t)t * NBKT + i] : 0;
  const int v1 = (t + 256 < NPBLK) ? blkbase[(size_t)(t + 256) * NBKT + i] : 0;
  const int s = v0 + v1;
  lds[t] = s;
  __syncthreads();
  for (int o = 1; o < 256; o <<= 1) {
    const int val = (t >= o) ? lds[t - o] : 0;
    __syncthreads();
    lds[t] += val;
    __syncthreads();
  }
  const int run = lds[t] - s;
  if (t == 255) gcount[i] = lds[255];
  if (t < NPBLK) blkbase[(size_t)t * NBKT + i] = run;
  if (t + 256 < NPBLK) blkbase[(size_t)(t + 256) * NBKT + i] = run + v0;
}

// ---------- part_scan: single-block exclusive scan of 782 bucket counts -----
__global__ __launch_bounds__(256) void part_scan(
    const int* __restrict__ gcount, int* __restrict__ gbase) {
  __shared__ int lds[256];
  const int t = threadIdx.x;
  int v[4];
  int s = 0;
#pragma unroll
  for (int j = 0; j < 4; ++j) {
    const int idx = t * 4 + j;
    v[j] = (idx < NBKT) ? gcount[idx] : 0;
    s += v[j];
  }
  lds[t] = s;
  __syncthreads();
  for (int o = 1; o < 256; o <<= 1) {
    const int val = (t >= o) ? lds[t - o] : 0;
    __syncthreads();
    lds[t] += val;
    __syncthreads();
  }
  int run = lds[t] - s;
#pragma unroll
  for (int j = 0; j < 4; ++j) {
    const int idx = t * 4 + j;
    if (idx < NBKT) gbase[idx] = run;
    run += v[j];
  }
}

// ---------- fuseB: part_scatter (blocks 0..499) || gemm0 rows 50048+ --------
// pe[e] = src | (localdst << 17)   (src < 2^17, localdst < 128)
__global__ __launch_bounds__(256) void fuseB(
    const float* __restrict__ x, const _Float16* __restrict__ B0f,
    const float* __restrict__ b0,
    unsigned short* __restrict__ p0u, unsigned short* __restrict__ s0bu,
    const int* __restrict__ w, const int* __restrict__ flag,
    const int* __restrict__ gbase, const int* __restrict__ blkbase,
    int* __restrict__ pe) {
  __shared__ _Float16 lb[128 * 128];  // 32 KB (scatter path: cur[] scratch)
  const int tid = threadIdx.x;

  if (blockIdx.x < NPBLK) {
    int* cur = (int*)lb;
    const int t = tid, b = blockIdx.x;
    for (int i = t; i < NBKT; i += 256)
      cur[i] = gbase[i] + blkbase[(size_t)b * NBKT + i];
    __syncthreads();
    const int i64 = flag[0];
    const int pEnd = (b + 1) * PAIRS_PER_BLK;
    for (int p = b * PAIRS_PER_BLK + t; p < pEnd; p += 256) {
      int s0, s1, d0, d1;
      if (i64) {
        const int4 vs = *(const int4*)(w + 4 * (size_t)p);
        const int4 vd = *(const int4*)(w + 2 * (size_t)N_EDGES + 4 * (size_t)p);
        s0 = vs.x; s1 = vs.z;
        d0 = vd.x; d1 = vd.z;
      } else {
        const int2 vs = *(const int2*)(w + 2 * (size_t)p);
        const int2 vd = *(const int2*)(w + (size_t)N_EDGES + 2 * (size_t)p);
        s0 = vs.x; s1 = vs.y;
        d0 = vd.x; d1 = vd.y;
      }
      const int sl0 = atomicAdd(&cur[d0 >> 7], 1);
      pe[sl0] = s0 | ((d0 & 127) << 17);
      const int sl1 = atomicAdd(&cur[d1 >> 7], 1);
      pe[sl1] = s1 | ((d1 & 127) << 17);
    }
    return;
  }
  gemm0_body(blockIdx.x - NPBLK + G0TA, tid, lb, x, B0f, b0, p0u, s0bu);
}

// ---------- bucket_csr: per-bucket CSR build, padded to x4 with zero-row ----
__global__ __launch_bounds__(256) void bucket_csr(
    const int* __restrict__ pe, const int* __restrict__ gbase,
    const int* __restrict__ gcount, int* __restrict__ deg,
    int* __restrict__ off, int* __restrict__ sortedSrc) {
  __shared__ int ldeg[128];
  __shared__ int loff[128];
  __shared__ int lcur[128];
  const int t = threadIdx.x;
  const int bkt = blockIdx.x;
  const int nbase = bkt << 7;
  const int ebase = gbase[bkt];
  const int cnt = gcount[bkt];
  const int outbase = ebase + PADCAP * bkt;
  if (t < 128) ldeg[t] = 0;
  __syncthreads();
  for (int e = t; e < cnt; e += 256) {
    const int pv = pe[ebase + e];
    atomicAdd(&ldeg[(pv >> 17) & 127], 1);
  }
  __syncthreads();
  if (t < 128) loff[t] = (ldeg[t] + 3) & ~3;  // padded degree
  __syncthreads();
  for (int o = 1; o < 128; o <<= 1) {
    int v = 0;
    if (t >= o && t < 128) v = loff[t - o];
    __syncthreads();
    if (t < 128) loff[t] += v;
    __syncthreads();
  }
  if (t < 128) {
    const int pdeg = (ldeg[t] + 3) & ~3;
    const int ex = loff[t] - pdeg;
    lcur[t] = ex;
    const int n = nbase + t;
    if (n < N_NODES) {
      deg[n] = ldeg[t];
      off[n] = outbase + ex;
    }
  }
  __syncthreads();
  for (int e = t; e < cnt; e += 256) {
    const int pv = pe[ebase + e];
    const int ld = (pv >> 17) & 127;
    const int p = atomicAdd(&lcur[ld], 1);
    sortedSrc[outbase + p] = pv & 0x1FFFF;
  }
  __syncthreads();
  if (t < 128) {
    const int pdeg = (ldeg[t] + 3) & ~3;
    const int ex = loff[t] - pdeg;
    for (int q = ldeg[t]; q < pdeg; ++q)
      sortedSrc[outbase + ex + q] = N_NODES;  // zero row
  }
}

// ------- Layer 1 bf16 MFMA GEMM: [p1 | s1b] = h1 @ [Wn1 | Ws1] (+b1) --------
__global__ __launch_bounds__(256) void gemm1(
    const unsigned short* __restrict__ h1u, const unsigned short* __restrict__ B1u,
    const float* __restrict__ b1,
    unsigned short* __restrict__ p1u, unsigned short* __restrict__ s1bu) {
  __shared__ unsigned short lb[64 * 64];  // 8 KB
  const int tid = threadIdx.x;
  const int lane = tid & 63;
  const int wave = tid >> 6;
  const int rowbase = blockIdx.x * 64 + wave * 16;
  const int arow = rowbase + (lane & 15);
  const int rclamp = (arow < N_NODES) ? arow : 0;
  const int ko = (lane >> 4) << 3;

  short8 ah[2];
  {
    const unsigned short* ax = h1u + (size_t)rclamp * HID + ko;
    ah[0] = *(const short8*)ax;
    ah[1] = *(const short8*)(ax + 32);
  }
  {
    const uint4* gb = (const uint4*)B1u;
    for (int i = tid; i < 512; i += 256) {
      const int o = i << 4;
      const int sw = o ^ (((o >> 7) & 7) << 4);
      *(uint4*)((char*)lb + sw) = gb[i];
    }
  }
  __syncthreads();

  f32x4 acc[4];
#pragma unroll
  for (int ct = 0; ct < 4; ++ct) acc[ct] = (f32x4){0.f, 0.f, 0.f, 0.f};

#pragma unroll
  for (int ks = 0; ks < 2; ++ks) {
    const int kb = ks * 64 + (ko << 1);
#pragma unroll
    for (int ct = 0; ct < 4; ++ct) {
      const int n = ct * 16 + (lane & 15);
      const int boff = (n << 7) + kb;
      const int sb = boff ^ (((boff >> 7) & 7) << 4);
      const short8 bv = *(const short8*)((const char*)lb + sb);
      acc[ct] = __builtin_amdgcn_mfma_f32_16x16x32_bf16(ah[ks], bv, acc[ct], 0, 0, 0);
    }
  }
  const int rb4 = rowbase + ((lane >> 4) << 2);
  const int cc = lane & 15;
#pragma unroll
  for (int ct = 0; ct < 2; ++ct) {  // -> p1 (bf16)
#pragma unroll
    for (int j = 0; j < 4; ++j) {
      const int r = rb4 + j;
      if (r < N_NODES) p1u[(size_t)r * OUT_DIM + ct * 16 + cc] = bf16rne(acc[ct][j]);
    }
  }
#pragma unroll
  for (int ct = 2; ct < 4; ++ct) {  // -> s1bu (bf16 + bias)
#pragma unroll
    for (int j = 0; j < 4; ++j) {
      const int r = rb4 + j;
      if (r < N_NODES)
        s1bu[(size_t)r * OUT_DIM + (ct - 2) * 16 + cc] =
            bf16rne(acc[ct][j] + b1[(ct - 2) * 16 + cc]);
    }
  }
}

// ------- Fused layer-0 aggregate + mean + LN + ReLU -> h1u (2 nodes/wave) ---
// R14 form (VGPR 20, occ ~65%): maskless pad-to-4 with data-driven zero row.
__global__ __launch_bounds__(256) void aggc0(
    const int* __restrict__ sortedSrc, const int* __restrict__ off,
    const int* __restrict__ deg, const unsigned short* __restrict__ p0u,
    const unsigned short* __restrict__ s0bu, const float* __restrict__ g,
    const float* __restrict__ be, unsigned short* __restrict__ h1u) {
  const int lane = threadIdx.x & 63;
  const int h = lane >> 5;          // node half
  const int grp = (lane >> 3) & 3;  // 4 edge groups
  const int sl = lane & 7;          // 8 feature slices
  const int i = blockIdx.x * 8 + ((threadIdx.x >> 6) << 1) + h;
  const int st = off[i];
  const int dg = deg[i];
  const int dgp = (dg + 3) & ~3;
  const int dgmaxp = max(dgp, __shfl_xor(dgp, 32));
  float acc[8];
#pragma unroll
  for (int f = 0; f < 8; ++f) acc[f] = 0.f;

  for (int base = 0; base < dgmaxp; base += 32) {
    const int cntp = dgp - base;
    const int l5 = lane & 31;
    const int idx = (l5 < cntp) ? sortedSrc[st + base + l5] : N_NODES;
    const int cm = min(32, dgmaxp - base);  // multiple of 4
    for (int j = 0; j * 4 < cm; ++j) {
      const int e = j * 4 + grp;
      const int srcn = __shfl(idx, (h << 5) | e);
      const uint4 q = *(const uint4*)(p0u + (size_t)srcn * HID + sl * 8);
      acc[0] += uflo(q.x); acc[1] += ufhi(q.x);
      acc[2] += uflo(q.y); acc[3] += ufhi(q.y);
      acc[4] += uflo(q.z); acc[5] += ufhi(q.z);
      acc[6] += uflo(q.w); acc[7] += ufhi(q.w);
    }
  }
  // fold edge groups (xor over lane bits 3,4 — stays within node half)
#pragma unroll
  for (int mk = 8; mk < 32; mk <<= 1) {
#pragma unroll
    for (int f = 0; f < 8; ++f) acc[f] += __shfl_xor(acc[f], mk);
  }
  const float inv = 1.0f / fmaxf((float)dg, 1.0f);
  float z[8];
  const uint4 sbv = *(const uint4*)(s0bu + (size_t)i * HID + sl * 8);
  z[0] = uflo(sbv.x) + acc[0] * inv; z[1] = ufhi(sbv.x) + acc[1] * inv;
  z[2] = uflo(sbv.y) + acc[2] * inv; z[3] = ufhi(sbv.y) + acc[3] * inv;
  z[4] = uflo(sbv.z) + acc[4] * inv; z[5] = ufhi(sbv.z) + acc[5] * inv;
  z[6] = uflo(sbv.w) + acc[6] * inv; z[7] = ufhi(sbv.w) + acc[7] * inv;
  float pm = 0.f;
#pragma unroll
  for (int f = 0; f < 8; ++f) pm += z[f];
#pragma unroll
  for (int mk = 1; mk < 8; mk <<= 1) pm += __shfl_xor(pm, mk);
  const float mean = pm * (1.0f / 64.0f);
  float pv = 0.f;
#pragma unroll
  for (int f = 0; f < 8; ++f) {
    z[f] -= mean;
    pv += z[f] * z[f];
  }
#pragma unroll
  for (int mk = 1; mk < 8; mk <<= 1) pv += __shfl_xor(pv, mk);
  const float rstd = rsqrtf(pv * (1.0f / 64.0f) + LN_EPS);
  if (grp == 0) {
    const float4 gv0 = *(const float4*)(g + sl * 8);
    const float4 gv1 = *(const float4*)(g + sl * 8 + 4);
    const float4 bv0 = *(const float4*)(be + sl * 8);
    const float4 bv1 = *(const float4*)(be + sl * 8 + 4);
    uint4 ov;
    ov.x = pk(fmaxf(z[0] * rstd * gv0.x + bv0.x, 0.f),
              fmaxf(z[1] * rstd * gv0.y + bv0.y, 0.f));
    ov.y = pk(fmaxf(z[2] * rstd * gv0.z + bv0.z, 0.f),
              fmaxf(z[3] * rstd * gv0.w + bv0.w, 0.f));
    ov.z = pk(fmaxf(z[4] * rstd * gv1.x + bv1.x, 0.f),
              fmaxf(z[5] * rstd * gv1.y + bv1.y, 0.f));
    ov.w = pk(fmaxf(z[6] * rstd * gv1.z + bv1.z, 0.f),
              fmaxf(z[7] * rstd * gv1.w + bv1.w, 0.f));
    *(uint4*)(h1u + (size_t)i * HID + sl * 8) = ov;
  }
}

// ------- Fused layer-1 aggregate + mean + LN + ReLU -> out (4 nodes/wave) ---
__global__ __launch_bounds__(256) void aggc1(
    const int* __restrict__ sortedSrc, const int* __restrict__ off,
    const int* __restrict__ deg, const unsigned short* __restrict__ p1u,
    const unsigned short* __restrict__ s1bu, const float* __restrict__ g,
    const float* __restrict__ be, float* __restrict__ out) {
  const int lane = threadIdx.x & 63;
  const int q4 = lane >> 4;         // node quarter
  const int grp = (lane >> 2) & 3;  // 4 edge groups
  const int sl = lane & 3;          // 4 feature slices
  const int i = blockIdx.x * 16 + ((threadIdx.x >> 6) << 2) + q4;
  const int st = off[i];
  const int dg = deg[i];
  const int dgp = (dg + 3) & ~3;
  int dm = max(dgp, __shfl_xor(dgp, 16));
  const int dgmaxp = max(dm, __shfl_xor(dm, 32));
  float acc[8];
#pragma unroll
  for (int f = 0; f < 8; ++f) acc[f] = 0.f;

  for (int base = 0; base < dgmaxp; base += 16) {
    const int cntp = dgp - base;
    const int l4 = lane & 15;
    const int idx = (l4 < cntp) ? sortedSrc[st + base + l4] : N_NODES;
    const int cm = min(16, dgmaxp - base);  // multiple of 4
    for (int j = 0; j * 4 < cm; ++j) {
      const int e = j * 4 + grp;
      const int srcn = __shfl(idx, (q4 << 4) | e);
      const uint4 qv = *(const uint4*)(p1u + (size_t)srcn * OUT_DIM + sl * 8);
      acc[0] += uflo(qv.x); acc[1] += ufhi(qv.x);
      acc[2] += uflo(qv.y); acc[3] += ufhi(qv.y);
      acc[4] += uflo(qv.z); acc[5] += ufhi(qv.z);
      acc[6] += uflo(qv.w); acc[7] += ufhi(qv.w);
    }
  }
  // fold edge groups (xor over lane bits 2,3 — stays within node quarter)
#pragma unroll
  for (int mk = 4; mk < 16; mk <<= 1) {
#pragma unroll
    for (int f = 0; f < 8; ++f) acc[f] += __shfl_xor(acc[f], mk);
  }
  const float inv = 1.0f / fmaxf((float)dg, 1.0f);
  float z[8];
  const uint4 sbv = *(const uint4*)(s1bu + (size_t)i * OUT_DIM + sl * 8);
  z[0] = uflo(sbv.x) + acc[0] * inv; z[1] = ufhi(sbv.x) + acc[1] * inv;
  z[2] = uflo(sbv.y) + acc[2] * inv; z[3] = ufhi(sbv.y) + acc[3] * inv;
  z[4] = uflo(sbv.z) + acc[4] * inv; z[5] = ufhi(sbv.z) + acc[5] * inv;
  z[6] = uflo(sbv.w) + acc[6] * inv; z[7] = ufhi(sbv.w) + acc[7] * inv;
  float pm = 0.f;
#pragma unroll
  for (int f = 0; f < 8; ++f) pm += z[f];
#pragma unroll
  for (int mk = 1; mk < 4; mk <<= 1) pm += __shfl_xor(pm, mk);
  const float mean = pm * (1.0f / 32.0f);
  float pv = 0.f;
#pragma unroll
  for (int f = 0; f < 8; ++f) {
    z[f] -= mean;
    pv += z[f] * z[f];
  }
#pragma unroll
  for (int mk = 1; mk < 4; mk <<= 1) pv += __shfl_xor(pv, mk);
  const float rstd = rsqrtf(pv * (1.0f / 32.0f) + LN_EPS);
  if (grp == 0) {
    const float4 gv0 = *(const float4*)(g + sl * 8);
    const float4 gv1 = *(const float4*)(g + sl * 8 + 4);
    const float4 bv0 = *(const float4*)(be + sl * 8);
    const float4 bv1 = *(const float4*)(be + sl * 8 + 4);
    float4 o0, o1;
    o0.x = fmaxf(z[0] * rstd * gv0.x + bv0.x, 0.f);
    o0.y = fmaxf(z[1] * rstd * gv0.y + bv0.y, 0.f);
    o0.z = fmaxf(z[2] * rstd * gv0.z + bv0.z, 0.f);
    o0.w = fmaxf(z[3] * rstd * gv0.w + bv0.w, 0.f);
    o1.x = fmaxf(z[4] * rstd * gv1.x + bv1.x, 0.f);
    o1.y = fmaxf(z[5] * rstd * gv1.y + bv1.y, 0.f);
    o1.z = fmaxf(z[6] * rstd * gv1.z + bv1.z, 0.f);
    o1.w = fmaxf(z[7] * rstd * gv1.w + bv1.w, 0.f);
    *(float4*)(out + (size_t)i * OUT_DIM + sl * 8) = o0;
    *(float4*)(out + (size_t)i * OUT_DIM + sl * 8 + 4) = o1;
  }
}

extern "C" void kernel_launch(void* const* d_in, const int* in_sizes, int n_in,
                              void* d_out, int out_size, void* d_ws, size_t ws_size,
                              hipStream_t stream) {
  const float* x       = (const float*)d_in[0];
  const int*   edges   = (const int*)d_in[1];
  const float* Wself0  = (const float*)d_in[2];
  const float* Wneigh0 = (const float*)d_in[3];
  const float* b0      = (const float*)d_in[4];
  const float* g0      = (const float*)d_in[5];
  const float* be0     = (const float*)d_in[6];
  const float* Wself1  = (const float*)d_in[7];
  const float* Wneigh1 = (const float*)d_in[8];
  const float* b1      = (const float*)d_in[9];
  const float* g1      = (const float*)d_in[10];
  const float* be1     = (const float*)d_in[11];

  // ---- 256-byte-aligned workspace carve-out ----
  char* base = (char*)d_ws;
  size_t o = 0;
  auto carve = [&](size_t bytes) {
    char* p = base + o;
    o += (bytes + 255) & ~(size_t)255;
    return p;
  };
  int* flag      = (int*)carve(64 * 4);
  int* gcount    = (int*)carve(1024 * 4);
  int* gbase     = (int*)carve(1024 * 4);
  int* blkbase   = (int*)carve((size_t)NPBLK * NBKT * 4);
  int* deg       = (int*)carve((size_t)N_NODES * 4);
  int* off       = (int*)carve((size_t)N_NODES * 4);
  int* sortedSrc = (int*)carve(1950000 * 4);  // 1.6M + PADCAP*NBKT
  int* pe        = (int*)carve(6500000);      // 1.62M ints; later p1u overlay
  _Float16* B0f  = (_Float16*)carve(128 * 128 * 2);
  unsigned short* B1u = (unsigned short*)carve(64 * 64 * 2);
  unsigned short* p0u = (unsigned short*)carve(((size_t)N_NODES + 2) * HID * 2);
  unsigned short* s0bu = (unsigned short*)carve(((size_t)N_NODES + 2) * HID * 2);
  unsigned short* h1u = (unsigned short*)carve(((size_t)N_NODES + 2) * HID * 2);
  unsigned short* p1u = (unsigned short*)pe;   // overlay (pe dead after csr)
  unsigned short* s1bu = s0bu;                 // overlay (s0bu dead after aggc0)

  detcw<<<81, 256, 0, stream>>>(edges, flag, Wneigh0, Wself0, Wneigh1, Wself1,
                                B0f, B1u, p0u, p1u);
  fuseA<<<NPBLK + G0TA, 256, 0, stream>>>(x, B0f, b0, p0u, s0bu,
                                          edges, flag, blkbase);
  bscan<<<NBKT, 256, 0, stream>>>(blkbase, gcount);
  part_scan<<<1, 256, 0, stream>>>(gcount, gbase);
  fuseB<<<NPBLK + G0TB, 256, 0, stream>>>(x, B0f, b0, p0u, s0bu,
                                          edges, flag, gbase, blkbase, pe);
  bucket_csr<<<NBKT, 256, 0, stream>>>(pe, gbase, gcount, deg, off, sortedSrc);

  aggc0<<<N_NODES / 8, 256, 0, stream>>>(sortedSrc, off, deg, p0u, s0bu,
                                         g0, be0, h1u);
  gemm1<<<(N_NODES + 63) / 64, 256, 0, stream>>>(h1u, B1u, b1, p1u, s1bu);
  aggc1<<<N_NODES / 16, 256, 0, stream>>>(sortedSrc, off, deg, p1u, s1bu,
                                          g1, be1, (float*)d_out);
}